// Round 11
// baseline (426.286 us; speedup 1.0000x reference)
//
#include <hip/hip_runtime.h>

#define T_TOK 8192
#define D_IN  1024
#define H_DIM 2048
#define DOUT_ 1024
#define NEXP  8
#define NPAIR 16384
#define BM 128
#define BN 128
#define BK 32
#define MAX_TILES 136

using bf16x8 = __attribute__((ext_vector_type(8))) __bf16;
using f32x16 = __attribute__((ext_vector_type(16))) float;
using us8    = __attribute__((ext_vector_type(8))) unsigned short;

__device__ __forceinline__ unsigned short f2bf(float f) {
  unsigned int u = __float_as_uint(f);
  u += 0x7FFFu + ((u >> 16) & 1u);   // RNE
  return (unsigned short)(u >> 16);
}

__device__ __forceinline__ float bf2f(unsigned short b) {
  return __uint_as_float((unsigned int)b << 16);
}

__device__ __forceinline__ void gload16(const void* g, void* l) {
  __builtin_amdgcn_global_load_lds(
      (const __attribute__((address_space(1))) void*)g,
      (__attribute__((address_space(3))) void*)l, 16, 0, 0);
}

// Derive this block's (expert, tileStart, segBase, segN) from cnt[8] in
// registers (no meta-table cross-kernel communication).
struct TileInfo { int e, ts, segBase, segN; };
__device__ __forceinline__ bool tile_lookup(const int* __restrict__ cnt, int by, TileInfo& ti) {
  int tp = 0, acc = 0;
  ti.e = -1;
#pragma unroll
  for (int e = 0; e < NEXP; ++e) {
    int c = cnt[e];
    int nt = (c + BM - 1) / BM;
    if (ti.e < 0 && by < tp + nt) { ti.e = e; ti.ts = (by - tp) * BM; ti.segBase = acc; ti.segN = c; }
    tp += nt; acc += c;
  }
  return ti.e >= 0;
}

// ---------------- conversion fp32 -> bf16 (16B loads AND stores; proven) ----
__global__ void convert_kernel(const float* __restrict__ x, const float* __restrict__ wg,
                               const float* __restrict__ wu, const float* __restrict__ wd,
                               unsigned short* __restrict__ xb, unsigned short* __restrict__ wgb,
                               unsigned short* __restrict__ wub, unsigned short* __restrict__ wdb) {
  const long long nx = (long long)T_TOK * D_IN;
  const long long nw = (long long)NEXP * H_DIM * D_IN;
  const long long nd = (long long)NEXP * DOUT_ * H_DIM;
  const long long tot8 = (nx + 2 * nw + nd) >> 3;
  for (long long i = (long long)blockIdx.x * blockDim.x + threadIdx.x; i < tot8;
       i += (long long)gridDim.x * blockDim.x) {
    long long e = i << 3;
    const float* s; unsigned short* d; long long o;
    if (e < nx)              { s = x;  d = xb;  o = e; }
    else if (e < nx + nw)    { s = wg; d = wgb; o = e - nx; }
    else if (e < nx + 2*nw)  { s = wu; d = wub; o = e - nx - nw; }
    else                     { s = wd; d = wdb; o = e - nx - 2*nw; }
    float4 v0 = *(const float4*)(s + o);
    float4 v1 = *(const float4*)(s + o + 4);
    us8 b;
    b[0] = f2bf(v0.x); b[1] = f2bf(v0.y); b[2] = f2bf(v0.z); b[3] = f2bf(v0.w);
    b[4] = f2bf(v1.x); b[5] = f2bf(v1.y); b[6] = f2bf(v1.z); b[7] = f2bf(v1.w);
    *(us8*)(d + o) = b;
  }
}

// ---------------- dispatch build: single block, LDS atomics (proven, -110us) --
__global__ void dispatch_kernel(const int* __restrict__ idx, const float* __restrict__ w,
                                int* __restrict__ cnt, int* __restrict__ rows,
                                float* __restrict__ wts, int* __restrict__ inv) {
  __shared__ int hist[NEXP];
  __shared__ int base_s[NEXP];
  __shared__ int fill_s[NEXP];
  const int tid = threadIdx.x;   // 1024
  if (tid < NEXP) hist[tid] = 0;
  __syncthreads();
  for (int i = tid; i < NPAIR; i += 1024)
    atomicAdd(&hist[idx[i]], 1);
  __syncthreads();
  if (tid == 0) {
    int acc = 0;
#pragma unroll
    for (int e = 0; e < NEXP; ++e) { base_s[e] = acc; cnt[e] = hist[e]; acc += hist[e]; }
  }
  if (tid < NEXP) fill_s[tid] = 0;
  __syncthreads();
  for (int i = tid; i < NPAIR; i += 1024) {
    int e = idx[i];
    int p = atomicAdd(&fill_s[e], 1);
    int pos = base_s[e] + p;
    rows[pos] = i >> 1;       // token id (K=2)
    wts[pos] = w[i];
    inv[i] = pos;
  }
}

// ---------------- GEMM1: h = silu(x@Wg^T) * (x@Wu^T) ----------------
// ROUND-11 CHANGE (only one lever): 32x32x16 MFMA shape (4096 FLOP/cyc vs
// 3277; MFMA issue per wave-kstep 160->128 cyc; same LDS bytes). Sync
// structure reverted to the proven round-6 double-buffer 2-phase.
// A/B frag: lane holds row (lane&31), k-chunk 8*(lane>>5) within each k16.
// C/D frag (HW-verified m74/m101): col=lane&31, row=(r&3)+8*(r>>2)+4*(lane>>5).
__launch_bounds__(256, 2)
__global__ void gemm1_kernel(const unsigned short* __restrict__ xb,
                             const unsigned short* __restrict__ wgb,
                             const unsigned short* __restrict__ wub,
                             const int* __restrict__ cnt, const int* __restrict__ rows,
                             unsigned short* __restrict__ hbuf) {
  TileInfo ti;
  if (!tile_lookup(cnt, blockIdx.y, ti)) return;
  const int tid = threadIdx.x;
  const int e = ti.e, ts = ti.ts, segBase = ti.segBase, segN = ti.segN;
  const int ncol0 = blockIdx.x * BN;

  __shared__ unsigned short lds[2][3][BM][BK];   // A, Bg, Bu double-buffered: 48 KiB
  __shared__ int rows_s[BM];

  if (tid < BM) {
    int r = ts + tid;
    rows_s[tid] = rows[segBase + (r < segN ? r : 0)];
  }
  __syncthreads();

  const int r0 = tid >> 2, r1 = 64 + (tid >> 2);
  const int kq = (tid & 3) * 8;   // bf16 elements
  const int tok0 = rows_s[r0], tok1 = rows_s[r1];
  const unsigned short* ag0 = xb + (size_t)tok0 * D_IN + kq;
  const unsigned short* ag1 = xb + (size_t)tok1 * D_IN + kq;
  const unsigned short* wge = wgb + (size_t)e * H_DIM * D_IN;
  const unsigned short* wue = wub + (size_t)e * H_DIM * D_IN;
  const unsigned short* bg0 = wge + (size_t)(ncol0 + r0) * D_IN + kq;
  const unsigned short* bg1 = wge + (size_t)(ncol0 + r1) * D_IN + kq;
  const unsigned short* bu0 = wue + (size_t)(ncol0 + r0) * D_IN + kq;
  const unsigned short* bu1 = wue + (size_t)(ncol0 + r1) * D_IN + kq;

#define STAGE1(b, k0) do { \
    gload16(ag0 + (k0), &lds[b][0][r0][kq]); \
    gload16(ag1 + (k0), &lds[b][0][r1][kq]); \
    gload16(bg0 + (k0), &lds[b][1][r0][kq]); \
    gload16(bg1 + (k0), &lds[b][1][r1][kq]); \
    gload16(bu0 + (k0), &lds[b][2][r0][kq]); \
    gload16(bu1 + (k0), &lds[b][2][r1][kq]); \
  } while (0)

  f32x16 gacc[2][2] = {};
  f32x16 uacc[2][2] = {};
  const int lane = tid & 63, wid = tid >> 6;
  const int wm = (wid >> 1) * 64, wn = (wid & 1) * 64;
  const int fr32 = lane & 31, fq32 = lane >> 5;

  STAGE1(0, 0);
  __syncthreads();
  for (int kt = 0; kt < D_IN / BK; ++kt) {
    const int cur = kt & 1;
    if (kt + 1 < D_IN / BK) STAGE1(cur ^ 1, (kt + 1) * BK);
    bf16x8 a[2][2], bg[2][2], bu[2][2];
#pragma unroll
    for (int mf = 0; mf < 2; ++mf)
#pragma unroll
      for (int ki = 0; ki < 2; ++ki)
        a[mf][ki]  = *(const bf16x8*)&lds[cur][0][wm + mf * 32 + fr32][ki * 16 + fq32 * 8];
#pragma unroll
    for (int nf = 0; nf < 2; ++nf)
#pragma unroll
      for (int ki = 0; ki < 2; ++ki) {
        bg[nf][ki] = *(const bf16x8*)&lds[cur][1][wn + nf * 32 + fr32][ki * 16 + fq32 * 8];
        bu[nf][ki] = *(const bf16x8*)&lds[cur][2][wn + nf * 32 + fr32][ki * 16 + fq32 * 8];
      }
#pragma unroll
    for (int ki = 0; ki < 2; ++ki)
#pragma unroll
      for (int mf = 0; mf < 2; ++mf)
#pragma unroll
        for (int nf = 0; nf < 2; ++nf) {
          gacc[mf][nf] = __builtin_amdgcn_mfma_f32_32x32x16_bf16(a[mf][ki], bg[nf][ki], gacc[mf][nf], 0, 0, 0);
          uacc[mf][nf] = __builtin_amdgcn_mfma_f32_32x32x16_bf16(a[mf][ki], bu[nf][ki], uacc[mf][nf], 0, 0, 0);
        }
    __syncthreads();
  }
#undef STAGE1

#pragma unroll
  for (int mf = 0; mf < 2; ++mf)
#pragma unroll
    for (int r = 0; r < 16; ++r) {
      int rloc = wm + mf * 32 + (r & 3) + 8 * (r >> 2) + 4 * fq32;
      int rseg = ts + rloc;
      if (rseg < segN) {
        size_t base = (size_t)(segBase + rseg) * H_DIM + ncol0 + wn + fr32;
#pragma unroll
        for (int nf = 0; nf < 2; ++nf) {
          float g = gacc[mf][nf][r], u = uacc[mf][nf][r];
          float h = g / (1.f + __expf(-g)) * u;   // silu(g)*u
          hbuf[base + nf * 32] = f2bf(h);
        }
      }
    }
}

// ---------------- GEMM2: wout[pos] = w * (h @ Wd^T) ----------------
// Round-6 proven config (BN=128 @ (256,4), bf16 wout) + 32x32x16 shape.
__launch_bounds__(256, 4)
__global__ void gemm2_kernel(const unsigned short* __restrict__ hbuf,
                             const unsigned short* __restrict__ wdb,
                             const int* __restrict__ cnt,
                             const float* __restrict__ wts, unsigned short* __restrict__ wout) {
  TileInfo ti;
  if (!tile_lookup(cnt, blockIdx.y, ti)) return;
  const int tid = threadIdx.x;
  const int e = ti.e, ts = ti.ts, segBase = ti.segBase, segN = ti.segN;
  const int ncol0 = blockIdx.x * BN;

  __shared__ unsigned short lds[2][2][BM][BK];   // 32 KiB

  const int r0 = tid >> 2, r1 = 64 + (tid >> 2);
  const int kq = (tid & 3) * 8;
  int ar0 = ts + r0; if (ar0 >= segN) ar0 = segN - 1;
  int ar1 = ts + r1; if (ar1 >= segN) ar1 = segN - 1;
  const unsigned short* ag0 = hbuf + (size_t)(segBase + ar0) * H_DIM + kq;
  const unsigned short* ag1 = hbuf + (size_t)(segBase + ar1) * H_DIM + kq;
  const unsigned short* wde = wdb + (size_t)e * DOUT_ * H_DIM;
  const unsigned short* bg0 = wde + (size_t)(ncol0 + r0) * H_DIM + kq;
  const unsigned short* bg1 = wde + (size_t)(ncol0 + r1) * H_DIM + kq;

#define STAGE2(b, k0) do { \
    gload16(ag0 + (k0), &lds[b][0][r0][kq]); \
    gload16(ag1 + (k0), &lds[b][0][r1][kq]); \
    gload16(bg0 + (k0), &lds[b][1][r0][kq]); \
    gload16(bg1 + (k0), &lds[b][1][r1][kq]); \
  } while (0)

  f32x16 acc[2][2] = {};
  const int lane = tid & 63, wid = tid >> 6;
  const int wm = (wid >> 1) * 64, wn = (wid & 1) * 64;
  const int fr32 = lane & 31, fq32 = lane >> 5;

  STAGE2(0, 0);
  __syncthreads();
  for (int kt = 0; kt < H_DIM / BK; ++kt) {
    const int cur = kt & 1;
    if (kt + 1 < H_DIM / BK) STAGE2(cur ^ 1, (kt + 1) * BK);
    bf16x8 a[2][2], b[2][2];
#pragma unroll
    for (int mf = 0; mf < 2; ++mf)
#pragma unroll
      for (int ki = 0; ki < 2; ++ki)
        a[mf][ki] = *(const bf16x8*)&lds[cur][0][wm + mf * 32 + fr32][ki * 16 + fq32 * 8];
#pragma unroll
    for (int nf = 0; nf < 2; ++nf)
#pragma unroll
      for (int ki = 0; ki < 2; ++ki)
        b[nf][ki] = *(const bf16x8*)&lds[cur][1][wn + nf * 32 + fr32][ki * 16 + fq32 * 8];
#pragma unroll
    for (int ki = 0; ki < 2; ++ki)
#pragma unroll
      for (int mf = 0; mf < 2; ++mf)
#pragma unroll
        for (int nf = 0; nf < 2; ++nf)
          acc[mf][nf] = __builtin_amdgcn_mfma_f32_32x32x16_bf16(a[mf][ki], b[nf][ki], acc[mf][nf], 0, 0, 0);
    __syncthreads();
  }
#undef STAGE2

#pragma unroll
  for (int mf = 0; mf < 2; ++mf)
#pragma unroll
    for (int r = 0; r < 16; ++r) {
      int rloc = wm + mf * 32 + (r & 3) + 8 * (r >> 2) + 4 * fq32;
      int rseg = ts + rloc;
      if (rseg < segN) {
        float w = wts[segBase + rseg];
        unsigned short* obase = wout + (size_t)(segBase + rseg) * DOUT_ + ncol0 + wn + fr32;
#pragma unroll
        for (int nf = 0; nf < 2; ++nf)
          obase[nf * 32] = f2bf(acc[mf][nf][r] * w);
      }
    }
}

// ---------------- combine: out[t] = wout[inv[2t]] + wout[inv[2t+1]] (bf16 in) ----
__global__ void combine_kernel(const unsigned short* __restrict__ wout, const int* __restrict__ inv,
                               float* __restrict__ out) {
  const int total = T_TOK * (DOUT_ / 4);           // 4-elem chunks
  for (int i = blockIdx.x * blockDim.x + threadIdx.x; i < total;
       i += gridDim.x * blockDim.x) {
    int t = i >> 8;                                 // DOUT/4 = 256 chunks per token
    int c4 = (i & 255) << 2;
    int p0 = inv[2 * t], p1 = inv[2 * t + 1];
    ushort4 a = *(const ushort4*)(wout + ((size_t)p0 << 10) + c4);
    ushort4 b = *(const ushort4*)(wout + ((size_t)p1 << 10) + c4);
    float4 r;
    r.x = bf2f(a.x) + bf2f(b.x);
    r.y = bf2f(a.y) + bf2f(b.y);
    r.z = bf2f(a.z) + bf2f(b.z);
    r.w = bf2f(a.w) + bf2f(b.w);
    *(float4*)(out + ((size_t)t << 10) + c4) = r;
  }
}

// ---------------- launch ----------------
extern "C" void kernel_launch(void* const* d_in, const int* in_sizes, int n_in,
                              void* d_out, int out_size, void* d_ws, size_t ws_size,
                              hipStream_t stream) {
  const float* x   = (const float*)d_in[0];
  const int*   idx = (const int*)d_in[1];
  const float* tkw = (const float*)d_in[2];
  const float* wg  = (const float*)d_in[3];
  const float* wu  = (const float*)d_in[4];
  const float* wd  = (const float*)d_in[5];
  float* out = (float*)d_out;

  char* p = (char*)d_ws;
  // wout (bf16, 33.5 MB) aliases xb+wgb: dead after gemm1, rewritten by
  // convert at the start of every call -> deterministic.
  unsigned short* wout = (unsigned short*)p;
  unsigned short* xb   = (unsigned short*)p; p += (size_t)T_TOK * D_IN * 2;
  unsigned short* wgb  = (unsigned short*)p; p += (size_t)NEXP * H_DIM * D_IN * 2;
  unsigned short* wub  = (unsigned short*)p; p += (size_t)NEXP * H_DIM * D_IN * 2;
  unsigned short* wdb  = (unsigned short*)p; p += (size_t)NEXP * DOUT_ * H_DIM * 2;
  unsigned short* hbuf = (unsigned short*)p; p += (size_t)NPAIR * H_DIM * 2;
  int*   rows = (int*)p;   p += NPAIR * 4;
  float* wts  = (float*)p; p += NPAIR * 4;
  int*   inv  = (int*)p;   p += NPAIR * 4;
  int*   cnt  = (int*)p;   p += NEXP * 4;

  convert_kernel<<<2048, 256, 0, stream>>>(x, wg, wu, wd, xb, wgb, wub, wdb);
  dispatch_kernel<<<1, 1024, 0, stream>>>(idx, tkw, cnt, rows, wts, inv);
  gemm1_kernel<<<dim3(H_DIM / BN, MAX_TILES), 256, 0, stream>>>(xb, wgb, wub, cnt, rows, hbuf);
  gemm2_kernel<<<dim3(DOUT_ / BN, MAX_TILES), 256, 0, stream>>>(hbuf, wdb, cnt, wts, wout);
  combine_kernel<<<2048, 256, 0, stream>>>(wout, inv, out);
}

// Round 12
// 390.030 us; speedup vs baseline: 1.0930x; 1.0930x over previous
//
#include <hip/hip_runtime.h>

#define T_TOK 8192
#define D_IN  1024
#define H_DIM 2048
#define DOUT_ 1024
#define NEXP  8
#define NPAIR 16384
#define BM 128
#define BN 128
#define BK 32
#define MAX_TILES 136

using bf16x8 = __attribute__((ext_vector_type(8))) __bf16;
using f32x4  = __attribute__((ext_vector_type(4))) float;
using us8    = __attribute__((ext_vector_type(8))) unsigned short;

__device__ __forceinline__ unsigned short f2bf(float f) {
  unsigned int u = __float_as_uint(f);
  u += 0x7FFFu + ((u >> 16) & 1u);   // RNE
  return (unsigned short)(u >> 16);
}

__device__ __forceinline__ float bf2f(unsigned short b) {
  return __uint_as_float((unsigned int)b << 16);
}

__device__ __forceinline__ void gload16(const void* g, void* l) {
  __builtin_amdgcn_global_load_lds(
      (const __attribute__((address_space(1))) void*)g,
      (__attribute__((address_space(3))) void*)l, 16, 0, 0);
}

// Derive this block's (expert, tileStart, segBase, segN) from cnt[8] in
// registers (no meta-table cross-kernel communication).
struct TileInfo { int e, ts, segBase, segN; };
__device__ __forceinline__ bool tile_lookup(const int* __restrict__ cnt, int by, TileInfo& ti) {
  int tp = 0, acc = 0;
  ti.e = -1;
#pragma unroll
  for (int e = 0; e < NEXP; ++e) {
    int c = cnt[e];
    int nt = (c + BM - 1) / BM;
    if (ti.e < 0 && by < tp + nt) { ti.e = e; ti.ts = (by - tp) * BM; ti.segBase = acc; ti.segN = c; }
    tp += nt; acc += c;
  }
  return ti.e >= 0;
}

// ---------------- conversion fp32 -> bf16 (16B loads AND stores; proven) ----
__global__ void convert_kernel(const float* __restrict__ x, const float* __restrict__ wg,
                               const float* __restrict__ wu, const float* __restrict__ wd,
                               unsigned short* __restrict__ xb, unsigned short* __restrict__ wgb,
                               unsigned short* __restrict__ wub, unsigned short* __restrict__ wdb) {
  const long long nx = (long long)T_TOK * D_IN;
  const long long nw = (long long)NEXP * H_DIM * D_IN;
  const long long nd = (long long)NEXP * DOUT_ * H_DIM;
  const long long tot8 = (nx + 2 * nw + nd) >> 3;
  for (long long i = (long long)blockIdx.x * blockDim.x + threadIdx.x; i < tot8;
       i += (long long)gridDim.x * blockDim.x) {
    long long e = i << 3;
    const float* s; unsigned short* d; long long o;
    if (e < nx)              { s = x;  d = xb;  o = e; }
    else if (e < nx + nw)    { s = wg; d = wgb; o = e - nx; }
    else if (e < nx + 2*nw)  { s = wu; d = wub; o = e - nx - nw; }
    else                     { s = wd; d = wdb; o = e - nx - 2*nw; }
    float4 v0 = *(const float4*)(s + o);
    float4 v1 = *(const float4*)(s + o + 4);
    us8 b;
    b[0] = f2bf(v0.x); b[1] = f2bf(v0.y); b[2] = f2bf(v0.z); b[3] = f2bf(v0.w);
    b[4] = f2bf(v1.x); b[5] = f2bf(v1.y); b[6] = f2bf(v1.z); b[7] = f2bf(v1.w);
    *(us8*)(d + o) = b;
  }
}

// ---------------- dispatch build: single block, LDS atomics (proven, -110us) --
__global__ void dispatch_kernel(const int* __restrict__ idx, const float* __restrict__ w,
                                int* __restrict__ cnt, int* __restrict__ rows,
                                float* __restrict__ wts, int* __restrict__ inv) {
  __shared__ int hist[NEXP];
  __shared__ int base_s[NEXP];
  __shared__ int fill_s[NEXP];
  const int tid = threadIdx.x;   // 1024
  if (tid < NEXP) hist[tid] = 0;
  __syncthreads();
  for (int i = tid; i < NPAIR; i += 1024)
    atomicAdd(&hist[idx[i]], 1);
  __syncthreads();
  if (tid == 0) {
    int acc = 0;
#pragma unroll
    for (int e = 0; e < NEXP; ++e) { base_s[e] = acc; cnt[e] = hist[e]; acc += hist[e]; }
  }
  if (tid < NEXP) fill_s[tid] = 0;
  __syncthreads();
  for (int i = tid; i < NPAIR; i += 1024) {
    int e = idx[i];
    int p = atomicAdd(&fill_s[e], 1);
    int pos = base_s[e] + p;
    rows[pos] = i >> 1;       // token id (K=2)
    wts[pos] = w[i];
    inv[i] = pos;
  }
}

// ---------------- GEMM1: h = silu(x@Wg^T) * (x@Wu^T) ----------------
// PROVEN CONFIG (measured 205-207 us across rounds 1/4/6/7/9): 16x16x32,
// double-buffer 2-phase, (256,2)/VGPR 100. Probed-null/negative on this
// kernel: (256,3) cap (+55us x2), T1 swizzle (+12us), T2 source-swizzle
// (neutral), counted-vmcnt triple-buffer (neutral), 32x32x16 (+34us from
// 16-way LDS conflicts). 8-way conflict (1.3e7) is hidden at 2 blocks/CU.
__launch_bounds__(256, 2)
__global__ void gemm1_kernel(const unsigned short* __restrict__ xb,
                             const unsigned short* __restrict__ wgb,
                             const unsigned short* __restrict__ wub,
                             const int* __restrict__ cnt, const int* __restrict__ rows,
                             unsigned short* __restrict__ hbuf) {
  TileInfo ti;
  if (!tile_lookup(cnt, blockIdx.y, ti)) return;
  const int tid = threadIdx.x;
  const int e = ti.e, ts = ti.ts, segBase = ti.segBase, segN = ti.segN;
  const int ncol0 = blockIdx.x * BN;

  __shared__ unsigned short lds[2][3][BM][BK];   // A, Bg, Bu double-buffered: 48 KiB
  __shared__ int rows_s[BM];

  if (tid < BM) {
    int r = ts + tid;
    rows_s[tid] = rows[segBase + (r < segN ? r : 0)];
  }
  __syncthreads();

  const int r0 = tid >> 2, r1 = 64 + (tid >> 2);
  const int kq = (tid & 3) * 8;   // bf16 elements
  const int tok0 = rows_s[r0], tok1 = rows_s[r1];
  const unsigned short* ag0 = xb + (size_t)tok0 * D_IN + kq;
  const unsigned short* ag1 = xb + (size_t)tok1 * D_IN + kq;
  const unsigned short* wge = wgb + (size_t)e * H_DIM * D_IN;
  const unsigned short* wue = wub + (size_t)e * H_DIM * D_IN;
  const unsigned short* bg0 = wge + (size_t)(ncol0 + r0) * D_IN + kq;
  const unsigned short* bg1 = wge + (size_t)(ncol0 + r1) * D_IN + kq;
  const unsigned short* bu0 = wue + (size_t)(ncol0 + r0) * D_IN + kq;
  const unsigned short* bu1 = wue + (size_t)(ncol0 + r1) * D_IN + kq;

#define STAGE1(b, k0) do { \
    gload16(ag0 + (k0), &lds[b][0][r0][kq]); \
    gload16(ag1 + (k0), &lds[b][0][r1][kq]); \
    gload16(bg0 + (k0), &lds[b][1][r0][kq]); \
    gload16(bg1 + (k0), &lds[b][1][r1][kq]); \
    gload16(bu0 + (k0), &lds[b][2][r0][kq]); \
    gload16(bu1 + (k0), &lds[b][2][r1][kq]); \
  } while (0)

  f32x4 gacc[4][4] = {};
  f32x4 uacc[4][4] = {};
  const int lane = tid & 63, wid = tid >> 6;
  const int wm = (wid >> 1) * 64, wn = (wid & 1) * 64;
  const int fr = lane & 15, fq = lane >> 4;

  STAGE1(0, 0);
  __syncthreads();
  for (int kt = 0; kt < D_IN / BK; ++kt) {
    const int cur = kt & 1;
    if (kt + 1 < D_IN / BK) STAGE1(cur ^ 1, (kt + 1) * BK);
    bf16x8 af[4], bgf[4], buf_[4];
#pragma unroll
    for (int mf = 0; mf < 4; ++mf) af[mf]   = *(const bf16x8*)&lds[cur][0][wm + mf * 16 + fr][fq * 8];
#pragma unroll
    for (int nf = 0; nf < 4; ++nf) bgf[nf]  = *(const bf16x8*)&lds[cur][1][wn + nf * 16 + fr][fq * 8];
#pragma unroll
    for (int nf = 0; nf < 4; ++nf) buf_[nf] = *(const bf16x8*)&lds[cur][2][wn + nf * 16 + fr][fq * 8];
#pragma unroll
    for (int mf = 0; mf < 4; ++mf)
#pragma unroll
      for (int nf = 0; nf < 4; ++nf) {
        gacc[mf][nf] = __builtin_amdgcn_mfma_f32_16x16x32_bf16(af[mf], bgf[nf],  gacc[mf][nf], 0, 0, 0);
        uacc[mf][nf] = __builtin_amdgcn_mfma_f32_16x16x32_bf16(af[mf], buf_[nf], uacc[mf][nf], 0, 0, 0);
      }
    __syncthreads();
  }
#undef STAGE1

#pragma unroll
  for (int mf = 0; mf < 4; ++mf)
#pragma unroll
    for (int i = 0; i < 4; ++i) {
      int rloc = wm + mf * 16 + fq * 4 + i;
      int rseg = ts + rloc;
      if (rseg < segN) {
        size_t base = (size_t)(segBase + rseg) * H_DIM + ncol0 + wn;
#pragma unroll
        for (int nf = 0; nf < 4; ++nf) {
          float g = gacc[mf][nf][i], u = uacc[mf][nf][i];
          float h = g / (1.f + __expf(-g)) * u;   // silu(g)*u
          hbuf[base + nf * 16 + fr] = f2bf(h);
        }
      }
    }
}

// ---------------- GEMM2: wout[pos] = w * (h @ Wd^T) ----------------
// PROVEN CONFIG: BN=128 @ (256,4), bf16 wout. Probed-negative: BN=256@(256,2)
// (+40us), coarse 8-phase 256x256x64 (+13us, 1 blk/CU tail), 32x32x16 shape.
__launch_bounds__(256, 4)
__global__ void gemm2_kernel(const unsigned short* __restrict__ hbuf,
                             const unsigned short* __restrict__ wdb,
                             const int* __restrict__ cnt,
                             const float* __restrict__ wts, unsigned short* __restrict__ wout) {
  TileInfo ti;
  if (!tile_lookup(cnt, blockIdx.y, ti)) return;
  const int tid = threadIdx.x;
  const int e = ti.e, ts = ti.ts, segBase = ti.segBase, segN = ti.segN;
  const int ncol0 = blockIdx.x * BN;

  __shared__ unsigned short lds[2][2][BM][BK];   // 32 KiB

  const int r0 = tid >> 2, r1 = 64 + (tid >> 2);
  const int kq = (tid & 3) * 8;
  int ar0 = ts + r0; if (ar0 >= segN) ar0 = segN - 1;
  int ar1 = ts + r1; if (ar1 >= segN) ar1 = segN - 1;
  const unsigned short* ag0 = hbuf + (size_t)(segBase + ar0) * H_DIM + kq;
  const unsigned short* ag1 = hbuf + (size_t)(segBase + ar1) * H_DIM + kq;
  const unsigned short* wde = wdb + (size_t)e * DOUT_ * H_DIM;
  const unsigned short* bg0 = wde + (size_t)(ncol0 + r0) * H_DIM + kq;
  const unsigned short* bg1 = wde + (size_t)(ncol0 + r1) * H_DIM + kq;

#define STAGE2(b, k0) do { \
    gload16(ag0 + (k0), &lds[b][0][r0][kq]); \
    gload16(ag1 + (k0), &lds[b][0][r1][kq]); \
    gload16(bg0 + (k0), &lds[b][1][r0][kq]); \
    gload16(bg1 + (k0), &lds[b][1][r1][kq]); \
  } while (0)

  f32x4 acc[4][4] = {};
  const int lane = tid & 63, wid = tid >> 6;
  const int wm = (wid >> 1) * 64, wn = (wid & 1) * 64;
  const int fr = lane & 15, fq = lane >> 4;

  STAGE2(0, 0);
  __syncthreads();
  for (int kt = 0; kt < H_DIM / BK; ++kt) {
    const int cur = kt & 1;
    if (kt + 1 < H_DIM / BK) STAGE2(cur ^ 1, (kt + 1) * BK);
    bf16x8 af[4], bf[4];
#pragma unroll
    for (int mf = 0; mf < 4; ++mf) af[mf] = *(const bf16x8*)&lds[cur][0][wm + mf * 16 + fr][fq * 8];
#pragma unroll
    for (int nf = 0; nf < 4; ++nf) bf[nf] = *(const bf16x8*)&lds[cur][1][wn + nf * 16 + fr][fq * 8];
#pragma unroll
    for (int mf = 0; mf < 4; ++mf)
#pragma unroll
      for (int nf = 0; nf < 4; ++nf)
        acc[mf][nf] = __builtin_amdgcn_mfma_f32_16x16x32_bf16(af[mf], bf[nf], acc[mf][nf], 0, 0, 0);
    __syncthreads();
  }
#undef STAGE2

#pragma unroll
  for (int mf = 0; mf < 4; ++mf)
#pragma unroll
    for (int i = 0; i < 4; ++i) {
      int rloc = wm + mf * 16 + fq * 4 + i;
      int rseg = ts + rloc;
      if (rseg < segN) {
        float w = wts[segBase + rseg];
        unsigned short* obase = wout + (size_t)(segBase + rseg) * DOUT_ + ncol0 + wn;
#pragma unroll
        for (int nf = 0; nf < 4; ++nf)
          obase[nf * 16 + fr] = f2bf(acc[mf][nf][i] * w);
      }
    }
}

// ---------------- combine: out[t] = wout[inv[2t]] + wout[inv[2t+1]] (bf16 in) ----
__global__ void combine_kernel(const unsigned short* __restrict__ wout, const int* __restrict__ inv,
                               float* __restrict__ out) {
  const int total = T_TOK * (DOUT_ / 4);           // 4-elem chunks
  for (int i = blockIdx.x * blockDim.x + threadIdx.x; i < total;
       i += gridDim.x * blockDim.x) {
    int t = i >> 8;                                 // DOUT/4 = 256 chunks per token
    int c4 = (i & 255) << 2;
    int p0 = inv[2 * t], p1 = inv[2 * t + 1];
    ushort4 a = *(const ushort4*)(wout + ((size_t)p0 << 10) + c4);
    ushort4 b = *(const ushort4*)(wout + ((size_t)p1 << 10) + c4);
    float4 r;
    r.x = bf2f(a.x) + bf2f(b.x);
    r.y = bf2f(a.y) + bf2f(b.y);
    r.z = bf2f(a.z) + bf2f(b.z);
    r.w = bf2f(a.w) + bf2f(b.w);
    *(float4*)(out + ((size_t)t << 10) + c4) = r;
  }
}

// ---------------- launch ----------------
extern "C" void kernel_launch(void* const* d_in, const int* in_sizes, int n_in,
                              void* d_out, int out_size, void* d_ws, size_t ws_size,
                              hipStream_t stream) {
  const float* x   = (const float*)d_in[0];
  const int*   idx = (const int*)d_in[1];
  const float* tkw = (const float*)d_in[2];
  const float* wg  = (const float*)d_in[3];
  const float* wu  = (const float*)d_in[4];
  const float* wd  = (const float*)d_in[5];
  float* out = (float*)d_out;

  char* p = (char*)d_ws;
  // wout (bf16, 33.5 MB) aliases xb+wgb: dead after gemm1, rewritten by
  // convert at the start of every call -> deterministic.
  unsigned short* wout = (unsigned short*)p;
  unsigned short* xb   = (unsigned short*)p; p += (size_t)T_TOK * D_IN * 2;
  unsigned short* wgb  = (unsigned short*)p; p += (size_t)NEXP * H_DIM * D_IN * 2;
  unsigned short* wub  = (unsigned short*)p; p += (size_t)NEXP * H_DIM * D_IN * 2;
  unsigned short* wdb  = (unsigned short*)p; p += (size_t)NEXP * DOUT_ * H_DIM * 2;
  unsigned short* hbuf = (unsigned short*)p; p += (size_t)NPAIR * H_DIM * 2;
  int*   rows = (int*)p;   p += NPAIR * 4;
  float* wts  = (float*)p; p += NPAIR * 4;
  int*   inv  = (int*)p;   p += NPAIR * 4;
  int*   cnt  = (int*)p;   p += NEXP * 4;

  convert_kernel<<<2048, 256, 0, stream>>>(x, wg, wu, wd, xb, wgb, wub, wdb);
  dispatch_kernel<<<1, 1024, 0, stream>>>(idx, tkw, cnt, rows, wts, inv);
  gemm1_kernel<<<dim3(H_DIM / BN, MAX_TILES), 256, 0, stream>>>(xb, wgb, wub, cnt, rows, hbuf);
  gemm2_kernel<<<dim3(DOUT_ / BN, MAX_TILES), 256, 0, stream>>>(hbuf, wdb, cnt, wts, wout);
  combine_kernel<<<2048, 256, 0, stream>>>(wout, inv, out);
}